// Round 1
// baseline (1001.590 us; speedup 1.0000x reference)
//
#include <hip/hip_runtime.h>
#include <cmath>

struct K32 { float k[32]; };
struct K16 { float k[16]; };

#define THETA 10.0f

// ---------------- psp: thread-per-row FIR, LDS-staged coalesced I/O ----------------
__global__ __launch_bounds__(256)
void psp_kernel(const float* __restrict__ in, float* __restrict__ out,
                int nrows, K32 pk) {
  __shared__ float lds[256 * 51];
  const int rowBase = blockIdx.x * 256;
  const int tid = threadIdx.x;
  const int validRows = min(256, nrows - rowBase);
  const int validElems = validRows * 50;
  const float* gbase = in + (size_t)rowBase * 50;
  for (int i = tid; i < validElems; i += 256) lds[i + i / 50] = gbase[i];
  __syncthreads();
  if (tid < validRows) {
    float x[50];
#pragma unroll
    for (int t = 0; t < 50; ++t) x[t] = lds[tid * 51 + t];
#pragma unroll
    for (int t = 0; t < 50; ++t) {
      float acc = 0.f;
#pragma unroll
      for (int k = 31; k >= 0; --k)           // x-index ascending (oldest first)
        if (t - k >= 0) acc += x[t - k] * pk.k[k];
      lds[tid * 51 + t] = acc;
    }
  }
  __syncthreads();
  float* obase = out + (size_t)rowBase * 50;
  for (int i = tid; i < validElems; i += 256) obase[i] = lds[i + i / 50];
}

// ---------------- spike: thread-per-row sequential refractory, LDS-staged ----------------
__global__ __launch_bounds__(256)
void spike_kernel(const float* __restrict__ u, float* __restrict__ s,
                  int nrows, K16 rk) {
  __shared__ float lds[256 * 51];
  const int rowBase = blockIdx.x * 256;
  const int tid = threadIdx.x;
  const int validRows = min(256, nrows - rowBase);
  const int validElems = validRows * 50;
  const float* gbase = u + (size_t)rowBase * 50;
  for (int i = tid; i < validElems; i += 256) lds[i + i / 50] = gbase[i];
  __syncthreads();
  if (tid < validRows) {
    float buf[16];
#pragma unroll
    for (int j = 0; j < 16; ++j) buf[j] = 0.f;
#pragma unroll
    for (int t = 0; t < 50; ++t) {
      float v = lds[tid * 51 + t] + buf[t & 15];
      buf[t & 15] = 0.f;
      float sp = 0.f;
      if (v >= THETA) {
        sp = 1.f;
#pragma unroll
        for (int j = 0; j < 16; ++j) buf[(t + 1 + j) & 15] += rk.k[j];
      }
      lds[tid * 51 + t] = sp;
    }
  }
  __syncthreads();
  float* obase = s + (size_t)rowBase * 50;
  for (int i = tid; i < validElems; i += 256) obase[i] = lds[i + i / 50];
}

// ---------------- conv (stride 2, pad 1): wave = (n, ho, wo-tile), lane = t ----------------
template <int CIN, int COUT, int KK, int WT>
__global__ __launch_bounds__(256)
void conv_kernel(const float* __restrict__ x, const float* __restrict__ w,
                 float* __restrict__ u, int N, int Hin, int Win, int Hout, int Wout) {
  constexpr int XR = 2 * (WT - 1) + KK;
  const int wtiles = (Wout + WT - 1) / WT;
  const int wave = (blockIdx.x * 256 + threadIdx.x) >> 6;
  const int lane = threadIdx.x & 63;
  const int wt = wave % wtiles;
  const int rest = wave / wtiles;
  const int ho = rest % Hout;
  const int n = rest / Hout;
  if (n >= N) return;
  const int wo0 = wt * WT;
  const int tt = lane < 50 ? lane : 49;

  float acc[COUT][WT] = {};
  for (int c = 0; c < CIN; ++c) {
#pragma unroll
    for (int kh = 0; kh < KK; ++kh) {
      const int hi = 2 * ho + kh - 1;
      if ((unsigned)hi >= (unsigned)Hin) continue;   // zero padding
      float xr[XR];
#pragma unroll
      for (int i = 0; i < XR; ++i) {
        const int wi = 2 * wo0 - 1 + i;
        xr[i] = ((unsigned)wi < (unsigned)Win)
                    ? x[(((size_t)(n * CIN + c) * Hin + hi) * Win + wi) * 50 + tt]
                    : 0.f;
      }
#pragma unroll
      for (int co = 0; co < COUT; ++co) {
#pragma unroll
        for (int kw = 0; kw < KK; ++kw) {
          const float wv = w[((co * CIN + c) * KK + kh) * KK + kw];
#pragma unroll
          for (int wl = 0; wl < WT; ++wl)
            acc[co][wl] += xr[2 * wl + kw] * wv;
        }
      }
    }
  }
  if (lane < 50) {
#pragma unroll
    for (int co = 0; co < COUT; ++co)
#pragma unroll
      for (int wl = 0; wl < WT; ++wl) {
        const int wo = wo0 + wl;
        if (wo < Wout)
          u[(((size_t)(n * COUT + co) * Hout + ho) * Wout + wo) * 50 + lane] = acc[co][wl];
      }
  }
}

// ---------------- fused psp -> 2x2 sum-pool * 2.75 -> spike ----------------
// block = (n*C + c, ho); stages the two needed input h-rows, psp per staged row,
// then pool+spike per output wo.
__global__ __launch_bounds__(256)
void psp_pool_spike_kernel(const float* __restrict__ in, float* __restrict__ out,
                           int Hin, int Win, int Hout, int Wout,
                           K32 pk, K16 rk) {
  extern __shared__ float lds[];
  const int tid = threadIdx.x;
  const int ho = blockIdx.x % Hout;
  const int nc = blockIdx.x / Hout;
  const int Wu = 2 * Wout;
  const float* base = in + ((size_t)nc * Hin + 2 * ho) * Win * 50;
  const int nstage = 2 * Wu * 50;
  for (int i = tid; i < nstage; i += 256) {
    const int r = i / 50, t = i - r * 50;
    const int h = (r >= Wu) ? 1 : 0;
    const int w = r - h * Wu;
    lds[r * 51 + t] = base[((size_t)h * Win + w) * 50 + t];
  }
  __syncthreads();
  for (int r = tid; r < 2 * Wu; r += 256) {
    float x[50];
#pragma unroll
    for (int t = 0; t < 50; ++t) x[t] = lds[r * 51 + t];
#pragma unroll
    for (int t = 0; t < 50; ++t) {
      float acc = 0.f;
#pragma unroll
      for (int k = 31; k >= 0; --k)
        if (t - k >= 0) acc += x[t - k] * pk.k[k];
      lds[r * 51 + t] = acc;
    }
  }
  __syncthreads();
  float yrow[50];
  if (tid < Wout) {
    float buf[16];
#pragma unroll
    for (int j = 0; j < 16; ++j) buf[j] = 0.f;
    const int r00 = (2 * tid) * 51, r01 = (2 * tid + 1) * 51;
    const int r10 = (Wu + 2 * tid) * 51, r11 = (Wu + 2 * tid + 1) * 51;
#pragma unroll
    for (int t = 0; t < 50; ++t) {
      const float u0 = (((lds[r00 + t] + lds[r01 + t]) + lds[r10 + t]) + lds[r11 + t]) * 2.75f;
      float v = u0 + buf[t & 15];
      buf[t & 15] = 0.f;
      float sp = 0.f;
      if (v >= THETA) {
        sp = 1.f;
#pragma unroll
        for (int j = 0; j < 16; ++j) buf[(t + 1 + j) & 15] += rk.k[j];
      }
      yrow[t] = sp;
    }
  }
  __syncthreads();
  if (tid < Wout) {
#pragma unroll
    for (int t = 0; t < 50; ++t) lds[tid * 51 + t] = yrow[t];
  }
  __syncthreads();
  float* obase = out + ((size_t)nc * Hout + ho) * Wout * 50;
  const int nout = Wout * 50;
  for (int i = tid; i < nout; i += 256) obase[i] = lds[i + i / 50];
}

// ---------------- fc: wave per (n,o), lane = t, sequential c,h,w fold ----------------
__global__ __launch_bounds__(256)
void fc_kernel(const float* __restrict__ w, const float* __restrict__ u,
               float* __restrict__ uo) {
  const int wave = (blockIdx.x * 256 + threadIdx.x) >> 6;
  const int lane = threadIdx.x & 63;
  if (wave >= 8) return;
  const int o = wave & 1, n = wave >> 1;
  const int tt = lane < 50 ? lane : 49;
  const float* wrow = w + (size_t)o * 2048;
  const float* ub = u + (size_t)n * 2048 * 50;
  float acc = 0.f;
#pragma unroll 8
  for (int i = 0; i < 2048; ++i) acc += wrow[i] * ub[(size_t)i * 50 + tt];
  if (lane < 50) uo[(n * 2 + o) * 50 + lane] = acc;
}

// ---------------- tiny final spike (8 rows) ----------------
__global__ __launch_bounds__(64)
void spike_rows_kernel(const float* __restrict__ u, float* __restrict__ s,
                       int nrows, K16 rk) {
  const int r = blockIdx.x * 64 + threadIdx.x;
  if (r >= nrows) return;
  float buf[16];
#pragma unroll
  for (int j = 0; j < 16; ++j) buf[j] = 0.f;
#pragma unroll
  for (int t = 0; t < 50; ++t) {
    float v = u[(size_t)r * 50 + t] + buf[t & 15];
    buf[t & 15] = 0.f;
    float sp = 0.f;
    if (v >= THETA) {
      sp = 1.f;
#pragma unroll
      for (int j = 0; j < 16; ++j) buf[(t + 1 + j) & 15] += rk.k[j];
    }
    s[(size_t)r * 50 + t] = sp;
  }
}

extern "C" void kernel_launch(void* const* d_in, const int* in_sizes, int n_in,
                              void* d_out, int out_size, void* d_ws, size_t ws_size,
                              hipStream_t stream) {
  const float* xin = (const float*)d_in[0];  // [4,2,256,256,50]
  const float* w1  = (const float*)d_in[1];  // [8,2,5,5]
  const float* w2  = (const float*)d_in[2];  // [16,8,3,3]
  const float* w3  = (const float*)d_in[3];  // [32,16,3,3]
  const float* wfc = (const float*)d_in[4];  // [2,32,8,8]
  float* out = (float*)d_out;                // [4,2,1,1,50]

  float* R0 = (float*)d_ws;                  // 26,214,400 floats
  float* R1 = R0 + 26214400;                 // 25,806,400 floats

  K32 pk;
  for (int k = 0; k < 32; ++k)
    pk.k[k] = (float)(((double)k / 10.0) * exp(1.0 - (double)k / 10.0));
  K16 rk;
  for (int j = 0; j < 16; ++j) {
    const double tr = (double)(j + 1);
    rk.k[j] = (float)(-2.0 * 10.0 * tr * exp(1.0 - tr));
  }

  // 1. psp1: input -> R0
  {
    int rows = 4 * 2 * 256 * 256;
    psp_kernel<<<(rows + 255) / 256, 256, 0, stream>>>(xin, R0, rows, pk);
  }
  // 2. conv1: R0 -> R1 (u1 [4,8,127,127,50])
  {
    int waves = 4 * 127 * 32;
    conv_kernel<2, 8, 5, 4><<<(waves + 3) / 4, 256, 0, stream>>>(R0, w1, R1, 4, 256, 256, 127, 127);
  }
  // 3. spike1: R1 -> R0 (s1)
  {
    int rows = 4 * 8 * 127 * 127;
    spike_kernel<<<(rows + 255) / 256, 256, 0, stream>>>(R1, R0, rows, rk);
  }
  // 4. psp+pool+spike: R0 -> R1 (s2 [4,8,63,63,50])
  {
    int blocks = 4 * 8 * 63;
    psp_pool_spike_kernel<<<blocks, 256, 252 * 51 * 4, stream>>>(R0, R1, 127, 127, 63, 63, pk, rk);
  }
  // 5. psp3: R1 -> R0
  {
    int rows = 4 * 8 * 63 * 63;
    psp_kernel<<<(rows + 255) / 256, 256, 0, stream>>>(R1, R0, rows, pk);
  }
  // 6. conv2: R0 -> R1 (u2 [4,16,32,32,50])
  {
    int waves = 4 * 32 * 16;
    conv_kernel<8, 16, 3, 2><<<(waves + 3) / 4, 256, 0, stream>>>(R0, w2, R1, 4, 63, 63, 32, 32);
  }
  // 7. spike3: R1 -> R0 (s3)
  {
    int rows = 4 * 16 * 32 * 32;
    spike_kernel<<<(rows + 255) / 256, 256, 0, stream>>>(R1, R0, rows, rk);
  }
  // 8. psp+pool+spike: R0 -> R1 (s4 [4,16,16,16,50])
  {
    int blocks = 4 * 16 * 16;
    psp_pool_spike_kernel<<<blocks, 256, 64 * 51 * 4, stream>>>(R0, R1, 32, 32, 16, 16, pk, rk);
  }
  // 9. psp5: R1 -> R0
  {
    int rows = 4 * 16 * 16 * 16;
    psp_kernel<<<(rows + 255) / 256, 256, 0, stream>>>(R1, R0, rows, pk);
  }
  // 10. conv3: R0 -> R1 (u3 [4,32,8,8,50])
  {
    int waves = 4 * 8 * 8;
    conv_kernel<16, 32, 3, 1><<<(waves + 3) / 4, 256, 0, stream>>>(R0, w3, R1, 4, 16, 16, 8, 8);
  }
  // 11. spike5: R1 -> R0 (s5)
  {
    int rows = 4 * 32 * 8 * 8;
    spike_kernel<<<(rows + 255) / 256, 256, 0, stream>>>(R1, R0, rows, rk);
  }
  // 12. psp6: R0 -> R1
  {
    int rows = 4 * 32 * 8 * 8;
    psp_kernel<<<(rows + 255) / 256, 256, 0, stream>>>(R0, R1, rows, pk);
  }
  // 13. fc: (wfc, R1) -> R0 (u_fc [4,2,50])
  fc_kernel<<<2, 256, 0, stream>>>(wfc, R1, R0);
  // 14. final spike -> d_out
  spike_rows_kernel<<<1, 64, 0, stream>>>(R0, out, 8, rk);
}